// Round 7
// baseline (449.969 us; speedup 1.0000x reference)
//
#include <hip/hip_runtime.h>
#include <hip/hip_bf16.h>

typedef __bf16 bf16x8 __attribute__((ext_vector_type(8)));
typedef float  f32x4  __attribute__((ext_vector_type(4)));

#define B_   4
#define N_   4096
#define FIN  300
#define FOUT 300
#define FP   320   // padded feature dim (multiple of 32)
#define MT   64    // adjb tile rows
#define KT   64    // adjb tile cols
#define NMT  (N_/MT)
#define NKT  (N_/KT)
#define TILE_BYTES (MT*KT*2)   // 8192

// ws layout (bytes)
#define WT_OFF   0                    // Wt   bf16 [FP][FP]
#define D_OFF    (512*1024)           // d    fp32 [B_*N_]
#define TSC_OFF  (1024*1024)          // Tsc  bf16 [B_*N_][FP]
#define YT_OFF   (16*1024*1024)       // Yt   bf16 [B_][FP][N_]
#define ADJB_OFF (32*1024*1024)       // adjb bf16 tiled+swizzled [B_][NMT][NKT][8KB]
#define ADJB_BYTES ((size_t)B_ * N_ * N_ * 2)

#define SB() __builtin_amdgcn_sched_barrier(0)

__device__ __forceinline__ void gload_lds16(const void* g, void* l) {
    __builtin_amdgcn_global_load_lds((const __attribute__((address_space(1))) void*)g,
                                     (__attribute__((address_space(3))) void*)l, 16, 0, 0);
}

// ---------------- K0: Wt[f][k] = bf16(W[k][f]), zero-padded ----------------
__global__ void k_wt(const float* __restrict__ W, __bf16* __restrict__ Wt) {
    int t = blockIdx.x * 256 + threadIdx.x;
    if (t >= FP * FP) return;
    int f = t / FP, k = t - f * FP;
    float v = (f < FOUT && k < FIN) ? W[k * FOUT + f] : 0.0f;
    Wt[t] = (__bf16)v;
}

// ---------------- K1a: rowsum only (fallback path) -------------------------
__global__ void k_rowsum(const float* __restrict__ adj, float* __restrict__ d) {
    int row  = blockIdx.x * 4 + (threadIdx.x >> 6);
    int lane = threadIdx.x & 63;
    const float4* p = (const float4*)(adj + (size_t)row * N_);
    float s = 0.0f;
#pragma unroll
    for (int it = 0; it < 16; ++it) {
        float4 v = p[it * 64 + lane];
        s += v.x + v.y + v.z + v.w;
    }
#pragma unroll
    for (int off = 32; off; off >>= 1) s += __shfl_xor(s, off);
    if (lane == 0) d[row] = rsqrtf(s + 1.0f);
}

// ---------------- K1b: rowsum + tiled/swizzled bf16 copy of adj ------------
// Tile layout: adjb[(b*NMT+mt)*NKT + kt] is 8 KB = rows [mloc][64 bf16],
// with 16B chunk c stored at byte  mloc*128 + (c*16 ^ ((mloc&7)<<4)).
__global__ void k_rowsum_cvt(const float* __restrict__ adj, float* __restrict__ d,
                             char* __restrict__ adjb) {
    int g    = blockIdx.x * 4 + (threadIdx.x >> 6);   // global row 0..B_*N_-1
    int lane = threadIdx.x & 63;                      // = kt
    int b    = g >> 12;
    int row  = g & (N_ - 1);
    int mt   = row >> 6, mloc = row & 63;
    const float4* p = (const float4*)(adj + (size_t)g * N_) + lane * 16;
    float4 v[16];
#pragma unroll
    for (int i = 0; i < 16; ++i) v[i] = p[i];
    float s = 0.0f;
#pragma unroll
    for (int i = 0; i < 16; ++i) s += v[i].x + v[i].y + v[i].z + v[i].w;
    char* tb = adjb + (size_t)((b * NMT + mt) * NKT + lane) * TILE_BYTES + mloc * 128;
    int sw = (mloc & 7) << 4;
#pragma unroll
    for (int c = 0; c < 8; ++c) {
        float4 v0 = v[2 * c], v1 = v[2 * c + 1];
        bf16x8 o;
        o[0] = (__bf16)v0.x; o[1] = (__bf16)v0.y; o[2] = (__bf16)v0.z; o[3] = (__bf16)v0.w;
        o[4] = (__bf16)v1.x; o[5] = (__bf16)v1.y; o[6] = (__bf16)v1.z; o[7] = (__bf16)v1.w;
        *(bf16x8*)(tb + ((c * 16) ^ sw)) = o;
    }
#pragma unroll
    for (int off = 32; off; off >>= 1) s += __shfl_xor(s, off);
    if (lane == 0) d[g] = rsqrtf(s + 1.0f);
}

// ---------------- K2: Tsc[j][k] = bf16(d[j]*text[j][k]), K zero-padded -----
__global__ void k_tsc(const float* __restrict__ text, const float* __restrict__ d,
                      __bf16* __restrict__ Tsc) {
    int t = blockIdx.x * 256 + threadIdx.x;
    int j = t / FP;
    int k = t - j * FP;
    float v = 0.0f;
    if (k < FIN) v = d[j] * text[(size_t)j * FIN + k];
    Tsc[t] = (__bf16)v;
}

// ---------------- K3: Yt[b][f][j] = sum_k Wt[f][k]*Tsc[b,j][k] -------------
__global__ __launch_bounds__(256) void k_y(const __bf16* __restrict__ Wt,
                                           const __bf16* __restrict__ Tsc,
                                           __bf16* __restrict__ Yt) {
    int b    = blockIdx.y;
    int j0   = blockIdx.x * 64;
    int wave = threadIdx.x >> 6, lane = threadIdx.x & 63;
    int lr = lane & 15, lg = lane >> 4;
    f32x4 acc[5][4] = {};
    for (int k0 = 0; k0 < FP; k0 += 32) {
        bf16x8 a[5], bb[4];
#pragma unroll
        for (int fi = 0; fi < 5; ++fi) {
            int f = (wave * 5 + fi) * 16 + lr;
            a[fi] = *(const bf16x8*)(Wt + (size_t)f * FP + k0 + lg * 8);
        }
#pragma unroll
        for (int ji = 0; ji < 4; ++ji) {
            int j = j0 + ji * 16 + lr;
            bb[ji] = *(const bf16x8*)(Tsc + ((size_t)(b * N_ + j)) * FP + k0 + lg * 8);
        }
#pragma unroll
        for (int fi = 0; fi < 5; ++fi)
#pragma unroll
            for (int ji = 0; ji < 4; ++ji)
                acc[fi][ji] = __builtin_amdgcn_mfma_f32_16x16x32_bf16(a[fi], bb[ji], acc[fi][ji], 0, 0, 0);
    }
#pragma unroll
    for (int fi = 0; fi < 5; ++fi)
#pragma unroll
        for (int ji = 0; ji < 4; ++ji)
#pragma unroll
            for (int r = 0; r < 4; ++r) {
                int f = (wave * 5 + fi) * 16 + lg * 4 + r;
                int j = j0 + ji * 16 + lr;
                Yt[((size_t)b * FP + f) * N_ + j] = (__bf16)acc[fi][ji][r];
            }
}

// ---------------- K4: out = d_i * (adj @ Yt) + bias — barrier-free pipe ----
// 512 thr = 8 waves, ALL sharing one 80-f B-panel (8m x 1n decomposition):
// wave w owns rows bx*128 + w*16 .. +16. All 8 waves issue IDENTICAL B-load
// addresses -> L1 dedups 7/8 of B traffic; L2/L3 B-stream drops to 336 MB.
// A: per-wave-private LDS ring (4 x 2 KB) via global_load_lds, stage dist 2,
// counted vmcnt(22) (= B(t)10 + A(t+1)2 + B(t+1)10 younger than A(t)).
// Rendezvous s_barrier every 4 phases bounds wave drift (protects L1 dedup);
// raw builtin barrier does NOT force vmcnt(0) (m201-verified pattern).
// Block decode: XCD key = (b, bx-lsb) so the 4 by-siblings that read the
// same adjb tiles land on the SAME XCD (L2 serves A re-reads).
__global__ __launch_bounds__(512) void k_gemm_pipe(const char* __restrict__ adjb,
                                                   const __bf16* __restrict__ Yt,
                                                   const float* __restrict__ d,
                                                   const float* __restrict__ bias,
                                                   float* __restrict__ out) {
    __shared__ __align__(16) char smem[64 * 1024];
    const int bid  = blockIdx.x;              // 0..511
    const int s_   = bid & 7;                 // XCD slice
    const int b    = s_ >> 1;                 // batch 0..3
    const int bxl  = s_ & 1;
    const int r_   = bid >> 3;                // 0..63
    const int by   = r_ & 3;                  // 0..3 (80-col f panel)
    const int bx   = (r_ >> 2) * 2 + bxl;     // 0..31 (128-row m block)
    const int w = threadIdx.x >> 6, lane = threadIdx.x & 63;
    const int lr = lane & 15, lg = lane >> 4;

    // wave w's 16 rows: global rows bx*128 + w*16; adjb tile 2bx+(w>>2),
    // row offset (w&3)*16 within the 64-row tile.
    const int rowoff = (w & 3) * 16;
    const char* atile = adjb + (size_t)((b * NMT + 2 * bx + (w >> 2)) * NKT) * TILE_BYTES;

    // B row pointers (5 f-frags) — identical across all 8 waves.
    const __bf16* bp[5];
#pragma unroll
    for (int nt = 0; nt < 5; ++nt)
        bp[nt] = Yt + ((size_t)b * FP + by * 80 + nt * 16 + lr) * N_ + lg * 8;

    // wave-private LDS ring (4 x 2 KB) + swizzled read addresses
    char* ring = smem + w * 8192;
    uint32_t sbase = (uint32_t)(uintptr_t)(__attribute__((address_space(3))) char*)smem;
    const int swz = (lr & 7) << 4;
    uint32_t lds_rd0 = sbase + w * 8192 + lr * 128 + ((lg * 16) ^ swz);
    uint32_t lds_rd1 = sbase + w * 8192 + lr * 128 + (((4 + lg) * 16) ^ swz);

    f32x4 acc[5] = {};
    bf16x8 B0[5][2], B1[5][2];

#define STAGEA(u, kt) { \
    const char* gs = atile + (size_t)(kt) * TILE_BYTES + rowoff * 128 + lane * 16; \
    char* ls = ring + (u) * 2048; \
    gload_lds16(gs, ls); \
    gload_lds16(gs + 1024, ls + 1024); }

#define LOADB(BS, kt) { _Pragma("unroll") \
    for (int nt = 0; nt < 5; ++nt) { \
        BS[nt][0] = *(const bf16x8*)(bp[nt] + (size_t)(kt) * 64); \
        BS[nt][1] = *(const bf16x8*)(bp[nt] + (size_t)(kt) * 64 + 32); } }

// phase t: consume A ring slot u (=t&3) and B set BSc (=t&1);
// stage A(tA=t+2) into slot (u+2)&3; load B(tB=t+1) into BSn.
#define PHASE(u, BSc, BSn, WN, tA, tB)                                                 \
    {                                                                                  \
        SB();                                                                          \
        asm volatile("s_waitcnt vmcnt(" #WN ")");                                      \
        SB();                                                                          \
        bf16x8 af0, af1;                                                               \
        asm volatile("ds_read_b128 %0, %1" : "=v"(af0) : "v"(lds_rd0 + (u) * 2048));   \
        asm volatile("ds_read_b128 %0, %1" : "=v"(af1) : "v"(lds_rd1 + (u) * 2048));   \
        asm volatile("s_waitcnt lgkmcnt(0)");                                          \
        SB();                                                                          \
        STAGEA(((u) + 2) & 3, tA)                                                      \
        LOADB(BSn, tB)                                                                 \
        SB();                                                                          \
        _Pragma("unroll")                                                              \
        for (int nt = 0; nt < 5; ++nt) {                                               \
            acc[nt] = __builtin_amdgcn_mfma_f32_16x16x32_bf16(af0, BSc[nt][0], acc[nt], 0, 0, 0); \
            acc[nt] = __builtin_amdgcn_mfma_f32_16x16x32_bf16(af1, BSc[nt][1], acc[nt], 0, 0, 0); \
        }                                                                              \
        SB();                                                                          \
    }

    // prologue: A(0), A(1), B(0)  -> queue = [A0(2), A1(2), B0(10)]
    STAGEA(0, 0)
    STAGEA(1, 1)
    LOADB(B0, 0)
    // peeled phases 0..3 (phase 0 uses WN=12: only A1+B0=12 ops younger than A0)
    PHASE(0, B0, B1, 12, 2, 1)
    PHASE(1, B1, B0, 22, 3, 2)
    PHASE(2, B0, B1, 22, 4, 3)
    PHASE(3, B1, B0, 22, 5, 4)
    __builtin_amdgcn_s_barrier();
    // steady state, phases t=tt+i: tA = t+2, tB = t+1 (clamped dummies at the
    // tail keep every phase at 12 VMEM ops so vmcnt(22) stays uniform).
    for (int tt = 4; tt < NKT; tt += 4) {
        int a0 = tt + 2 > NKT - 1 ? NKT - 1 : tt + 2;
        int a1 = tt + 3 > NKT - 1 ? NKT - 1 : tt + 3;
        int a2 = tt + 4 > NKT - 1 ? NKT - 1 : tt + 4;
        int a3 = tt + 5 > NKT - 1 ? NKT - 1 : tt + 5;
        int b0 = tt + 1 > NKT - 1 ? NKT - 1 : tt + 1;
        int b1 = tt + 2 > NKT - 1 ? NKT - 1 : tt + 2;
        int b2 = tt + 3 > NKT - 1 ? NKT - 1 : tt + 3;
        int b3 = tt + 4 > NKT - 1 ? NKT - 1 : tt + 4;
        PHASE(0, B0, B1, 22, a0, b0)
        PHASE(1, B1, B0, 22, a1, b1)
        PHASE(2, B0, B1, 22, a2, b2)
        PHASE(3, B1, B0, 22, a3, b3)
        __builtin_amdgcn_s_barrier();
    }

    // epilogue: scale by d_i, add bias, store (f < 300 only)
    const int rowb = bx * 128 + w * 16;
    float di[4];
#pragma unroll
    for (int r = 0; r < 4; ++r)
        di[r] = d[b * N_ + rowb + lg * 4 + r];
#pragma unroll
    for (int nt = 0; nt < 5; ++nt) {
        int f = by * 80 + nt * 16 + lr;
        if (f < FOUT) {
            float bv = bias[f];
#pragma unroll
            for (int r = 0; r < 4; ++r) {
                int i = rowb + lg * 4 + r;
                out[((size_t)b * N_ + i) * FOUT + f] = di[r] * acc[nt][r] + bv;
            }
        }
    }
#undef STAGEA
#undef LOADB
#undef PHASE
}

// ---------------- Fallback GEMM (fp32 adj direct; only if ws too small) ----
#define FB_LOAD(AV, BV, K0)                                                           \
    {                                                                                 \
        _Pragma("unroll")                                                             \
        for (int mi = 0; mi < 2; ++mi) {                                              \
            const float4* p = (const float4*)(adjf + (size_t)(rowbase + mi * 16 + lr) * N_ + (K0) + lg * 8); \
            float4 v0 = p[0], v1 = p[1];                                              \
            AV[mi][0] = (__bf16)v0.x; AV[mi][1] = (__bf16)v0.y;                       \
            AV[mi][2] = (__bf16)v0.z; AV[mi][3] = (__bf16)v0.w;                       \
            AV[mi][4] = (__bf16)v1.x; AV[mi][5] = (__bf16)v1.y;                       \
            AV[mi][6] = (__bf16)v1.z; AV[mi][7] = (__bf16)v1.w;                       \
        }                                                                             \
        _Pragma("unroll")                                                             \
        for (int nt = 0; nt < 10; ++nt) {                                             \
            int f = wn * 160 + nt * 16 + lr;                                          \
            BV[nt] = *(const bf16x8*)(Yb + (size_t)f * N_ + (K0) + lg * 8);           \
        }                                                                             \
    }
#define FB_MFMA(AV, BV)                                                               \
    {                                                                                 \
        _Pragma("unroll")                                                             \
        for (int mi = 0; mi < 2; ++mi)                                                \
            _Pragma("unroll")                                                         \
            for (int nt = 0; nt < 10; ++nt)                                           \
                acc[mi][nt] = __builtin_amdgcn_mfma_f32_16x16x32_bf16(AV[mi], BV[nt], acc[mi][nt], 0, 0, 0); \
    }

__global__ __launch_bounds__(256) void k_gemm_fb(const float* __restrict__ adj,
                                                 const __bf16* __restrict__ Yt,
                                                 const float* __restrict__ d,
                                                 const float* __restrict__ bias,
                                                 float* __restrict__ out) {
    int b    = blockIdx.y;
    int wave = threadIdx.x >> 6, lane = threadIdx.x & 63;
    int wm = wave & 1, wn = wave >> 1;
    int lr = lane & 15, lg = lane >> 4;
    int rowbase = blockIdx.x * 64 + wm * 32;
    const float*  adjf = adj + (size_t)b * N_ * N_;
    const __bf16* Yb   = Yt + (size_t)b * FP * N_;

    f32x4 acc[2][10] = {};
    bf16x8 aA[2], bA[10], aB[2], bB[10];

    FB_LOAD(aA, bA, 0)
    for (int k0 = 0; k0 < N_ - 64; k0 += 64) {
        FB_LOAD(aB, bB, k0 + 32)
        FB_MFMA(aA, bA)
        FB_LOAD(aA, bA, k0 + 64)
        FB_MFMA(aB, bB)
    }
    FB_LOAD(aB, bB, N_ - 32)
    FB_MFMA(aA, bA)
    FB_MFMA(aB, bB)

#pragma unroll
    for (int mi = 0; mi < 2; ++mi) {
        float di[4];
#pragma unroll
        for (int r = 0; r < 4; ++r)
            di[r] = d[b * N_ + rowbase + mi * 16 + lg * 4 + r];
#pragma unroll
        for (int nt = 0; nt < 10; ++nt) {
            int f = wn * 160 + nt * 16 + lr;
            if (f < FOUT) {
                float bv = bias[f];
#pragma unroll
                for (int r = 0; r < 4; ++r) {
                    int i = rowbase + mi * 16 + lg * 4 + r;
                    out[((size_t)b * N_ + i) * FOUT + f] = di[r] * acc[mi][nt][r] + bv;
                }
            }
        }
    }
}

extern "C" void kernel_launch(void* const* d_in, const int* in_sizes, int n_in,
                              void* d_out, int out_size, void* d_ws, size_t ws_size,
                              hipStream_t stream) {
    const float* text = (const float*)d_in[0];
    const float* adj  = (const float*)d_in[1];
    const float* W    = (const float*)d_in[2];
    const float* bias = (const float*)d_in[3];
    float* out = (float*)d_out;

    char* ws = (char*)d_ws;
    __bf16* Wt   = (__bf16*)(ws + WT_OFF);
    float*  dv   = (float*)(ws + D_OFF);
    __bf16* Tsc  = (__bf16*)(ws + TSC_OFF);
    __bf16* Yt   = (__bf16*)(ws + YT_OFF);
    char*   adjb = ws + ADJB_OFF;

    bool big = ws_size >= (size_t)ADJB_OFF + ADJB_BYTES;

    k_wt<<<dim3((FP * FP + 255) / 256), dim3(256), 0, stream>>>(W, Wt);
    if (big)
        k_rowsum_cvt<<<dim3(B_ * N_ / 4), dim3(256), 0, stream>>>(adj, dv, adjb);
    else
        k_rowsum<<<dim3(B_ * N_ / 4), dim3(256), 0, stream>>>(adj, dv);
    k_tsc<<<dim3(B_ * N_ * FP / 256), dim3(256), 0, stream>>>(text, dv, Tsc);
    k_y<<<dim3(N_ / 64, B_), dim3(256), 0, stream>>>(Wt, Tsc, Yt);
    if (big)
        k_gemm_pipe<<<dim3(512), dim3(512), 0, stream>>>(adjb, Yt, dv, bias, out);
    else
        k_gemm_fb<<<dim3(N_ / 64, B_), dim3(256), 0, stream>>>(adj, Yt, dv, bias, out);
}

// Round 8
// 232.868 us; speedup vs baseline: 1.9323x; 1.9323x over previous
//
#include <hip/hip_runtime.h>
#include <hip/hip_bf16.h>

typedef __bf16 bf16x8 __attribute__((ext_vector_type(8)));
typedef float  f32x4  __attribute__((ext_vector_type(4)));

#define B_   4
#define N_   4096
#define FIN  300
#define FOUT 300
#define FP   320   // padded feature dim (multiple of 32)
#define MT   64    // adjb tile rows
#define KT   64    // adjb tile cols
#define NMT  (N_/MT)
#define NKT  (N_/KT)
#define TILE_BYTES (MT*KT*2)   // 8192
#define STEP_BYTES 18432       // per-K-step LDS: A 8 KB + B 10 KB
#define YTILE 2048             // Ytt tile: 16 f x 64 k bf16

// ws layout (bytes)
#define WT_OFF   0                    // Wt   bf16 [FP][FP]
#define D_OFF    (512*1024)           // d    fp32 [B_*N_]
#define TSC_OFF  (1024*1024)          // Tsc  bf16 [B_*N_][FP]
#define YT_OFF   (16*1024*1024)       // Yt / Ytt (tiled)  ~10.5 MB
#define ADJB_OFF (32*1024*1024)       // adjb bf16 tiled+swizzled [B_][NMT][NKT][8KB]
#define ADJB_BYTES ((size_t)B_ * N_ * N_ * 2)

#define SB() __builtin_amdgcn_sched_barrier(0)

__device__ __forceinline__ void gload_lds16(const void* g, void* l) {
    __builtin_amdgcn_global_load_lds((const __attribute__((address_space(1))) void*)g,
                                     (__attribute__((address_space(3))) void*)l, 16, 0, 0);
}

// ---------------- K0: Wt[f][k] = bf16(W[k][f]), zero-padded ----------------
__global__ void k_wt(const float* __restrict__ W, __bf16* __restrict__ Wt) {
    int t = blockIdx.x * 256 + threadIdx.x;
    if (t >= FP * FP) return;
    int f = t / FP, k = t - f * FP;
    float v = (f < FOUT && k < FIN) ? W[k * FOUT + f] : 0.0f;
    Wt[t] = (__bf16)v;
}

// ---------------- K1a: rowsum only (fallback path) -------------------------
__global__ void k_rowsum(const float* __restrict__ adj, float* __restrict__ d) {
    int row  = blockIdx.x * 4 + (threadIdx.x >> 6);
    int lane = threadIdx.x & 63;
    const float4* p = (const float4*)(adj + (size_t)row * N_);
    float s = 0.0f;
#pragma unroll
    for (int it = 0; it < 16; ++it) {
        float4 v = p[it * 64 + lane];
        s += v.x + v.y + v.z + v.w;
    }
#pragma unroll
    for (int off = 32; off; off >>= 1) s += __shfl_xor(s, off);
    if (lane == 0) d[row] = rsqrtf(s + 1.0f);
}

// ---------------- K1b: rowsum + tiled/swizzled bf16 copy of adj ------------
// Tile layout: adjb[(b*NMT+mt)*NKT + kt] is 8 KB = rows [mloc][64 bf16],
// with 16B chunk c stored at byte  mloc*128 + (c*16 ^ ((mloc&7)<<4)).
__global__ void k_rowsum_cvt(const float* __restrict__ adj, float* __restrict__ d,
                             char* __restrict__ adjb) {
    int g    = blockIdx.x * 4 + (threadIdx.x >> 6);   // global row 0..B_*N_-1
    int lane = threadIdx.x & 63;                      // = kt
    int b    = g >> 12;
    int row  = g & (N_ - 1);
    int mt   = row >> 6, mloc = row & 63;
    const float4* p = (const float4*)(adj + (size_t)g * N_) + lane * 16;
    float4 v[16];
#pragma unroll
    for (int i = 0; i < 16; ++i) v[i] = p[i];
    float s = 0.0f;
#pragma unroll
    for (int i = 0; i < 16; ++i) s += v[i].x + v[i].y + v[i].z + v[i].w;
    char* tb = adjb + (size_t)((b * NMT + mt) * NKT + lane) * TILE_BYTES + mloc * 128;
    int sw = (mloc & 7) << 4;
#pragma unroll
    for (int c = 0; c < 8; ++c) {
        float4 v0 = v[2 * c], v1 = v[2 * c + 1];
        bf16x8 o;
        o[0] = (__bf16)v0.x; o[1] = (__bf16)v0.y; o[2] = (__bf16)v0.z; o[3] = (__bf16)v0.w;
        o[4] = (__bf16)v1.x; o[5] = (__bf16)v1.y; o[6] = (__bf16)v1.z; o[7] = (__bf16)v1.w;
        *(bf16x8*)(tb + ((c * 16) ^ sw)) = o;
    }
#pragma unroll
    for (int off = 32; off; off >>= 1) s += __shfl_xor(s, off);
    if (lane == 0) d[g] = rsqrtf(s + 1.0f);
}

// ---------------- K2: Tsc[j][k] = bf16(d[j]*text[j][k]), K zero-padded -----
__global__ void k_tsc(const float* __restrict__ text, const float* __restrict__ d,
                      __bf16* __restrict__ Tsc) {
    int t = blockIdx.x * 256 + threadIdx.x;
    int j = t / FP;
    int k = t - j * FP;
    float v = 0.0f;
    if (k < FIN) v = d[j] * text[(size_t)j * FIN + k];
    Tsc[t] = (__bf16)v;
}

// ---------------- K3a: plain Yt (fallback): Yt[b][f][j] --------------------
__global__ __launch_bounds__(256) void k_y(const __bf16* __restrict__ Wt,
                                           const __bf16* __restrict__ Tsc,
                                           __bf16* __restrict__ Yt) {
    int b    = blockIdx.y;
    int j0   = blockIdx.x * 64;
    int wave = threadIdx.x >> 6, lane = threadIdx.x & 63;
    int lr = lane & 15, lg = lane >> 4;
    f32x4 acc[5][4] = {};
    for (int k0 = 0; k0 < FP; k0 += 32) {
        bf16x8 a[5], bb[4];
#pragma unroll
        for (int fi = 0; fi < 5; ++fi) {
            int f = (wave * 5 + fi) * 16 + lr;
            a[fi] = *(const bf16x8*)(Wt + (size_t)f * FP + k0 + lg * 8);
        }
#pragma unroll
        for (int ji = 0; ji < 4; ++ji) {
            int j = j0 + ji * 16 + lr;
            bb[ji] = *(const bf16x8*)(Tsc + ((size_t)(b * N_ + j)) * FP + k0 + lg * 8);
        }
#pragma unroll
        for (int fi = 0; fi < 5; ++fi)
#pragma unroll
            for (int ji = 0; ji < 4; ++ji)
                acc[fi][ji] = __builtin_amdgcn_mfma_f32_16x16x32_bf16(a[fi], bb[ji], acc[fi][ji], 0, 0, 0);
    }
#pragma unroll
    for (int fi = 0; fi < 5; ++fi)
#pragma unroll
        for (int ji = 0; ji < 4; ++ji)
#pragma unroll
            for (int r = 0; r < 4; ++r) {
                int f = (wave * 5 + fi) * 16 + lg * 4 + r;
                int j = j0 + ji * 16 + lr;
                Yt[((size_t)b * FP + f) * N_ + j] = (__bf16)acc[fi][ji][r];
            }
}

// ---------------- K3b: tiled+swizzled Ytt for the pipelined GEMM -----------
// Ytt tile (ft, kt): 2 KB = 16 f-rows x 64 k bf16, tile idx (b*20+ft)*64+kt.
// Within tile: row floc (=f&15) at byte floc*128; 16-B chunk c of the row at
// byte (c*16 ^ ((floc&7)<<4)); elements (k&7) consecutive inside the chunk.
__global__ __launch_bounds__(256) void k_y_t(const __bf16* __restrict__ Wt,
                                             const __bf16* __restrict__ Tsc,
                                             char* __restrict__ Ytt) {
    int b    = blockIdx.y;
    int j0   = blockIdx.x * 64;
    int wave = threadIdx.x >> 6, lane = threadIdx.x & 63;
    int lr = lane & 15, lg = lane >> 4;
    f32x4 acc[5][4] = {};
    for (int k0 = 0; k0 < FP; k0 += 32) {
        bf16x8 a[5], bb[4];
#pragma unroll
        for (int fi = 0; fi < 5; ++fi) {
            int f = (wave * 5 + fi) * 16 + lr;
            a[fi] = *(const bf16x8*)(Wt + (size_t)f * FP + k0 + lg * 8);
        }
#pragma unroll
        for (int ji = 0; ji < 4; ++ji) {
            int j = j0 + ji * 16 + lr;
            bb[ji] = *(const bf16x8*)(Tsc + ((size_t)(b * N_ + j)) * FP + k0 + lg * 8);
        }
#pragma unroll
        for (int fi = 0; fi < 5; ++fi)
#pragma unroll
            for (int ji = 0; ji < 4; ++ji)
                acc[fi][ji] = __builtin_amdgcn_mfma_f32_16x16x32_bf16(a[fi], bb[ji], acc[fi][ji], 0, 0, 0);
    }
#pragma unroll
    for (int fi = 0; fi < 5; ++fi)
#pragma unroll
        for (int ji = 0; ji < 4; ++ji)
#pragma unroll
            for (int r = 0; r < 4; ++r) {
                int f = (wave * 5 + fi) * 16 + lg * 4 + r;   // 0..319
                int j = j0 + ji * 16 + lr;                   // 0..4095
                int ft = f >> 4, floc = f & 15;
                int kt = j >> 6, jloc = j & 63;
                size_t base = (size_t)((b * 20 + ft) * 64 + kt) * YTILE;
                int byte = floc * 128 + (((jloc >> 3) * 16) ^ ((floc & 7) << 4)) + (jloc & 7) * 2;
                *(__bf16*)(Ytt + base + byte) = (__bf16)acc[fi][ji][r];
            }
}

// ---------------- K4: out = d_i * (adj @ Yt) + bias ------------------------
// T3/T4 port: BOTH operands staged via global_load_lds into a ring of 3 LDS
// buffers (3 x 18 KB), stage distance 2, counted vmcnt — never vmcnt(0).
// 256 thr = 4 waves (8m x ... wave w owns rows bx*64 + w*16, all waves share
// the 80-f B panel). Per step each wave issues EXACTLY 5 gload_lds (20 total:
// 8 A-chunks + 10 B-chunks + 2 idempotent dummies) -> uniform vmcnt(10)
// waits only tile t while t+1/t+2 stay in flight. Raw s_barrier (no drain).
// A (adjb) and B (Ytt) are pre-swizzled in global memory: linear staging,
// swizzled ds_read (rule 21 both-sides).
// Block decode: bid = b*256 + by*64 + bx -> XCD = bx&7: the 4 by-siblings
// sharing an A-panel land on the same XCD and are co-resident.
__global__ __launch_bounds__(256) void k_gemm_pipe(const char* __restrict__ adjb,
                                                   const char* __restrict__ ytt,
                                                   const float* __restrict__ d,
                                                   const float* __restrict__ bias,
                                                   float* __restrict__ out) {
    __shared__ __align__(16) char smem[3 * STEP_BYTES];   // 54 KB -> 2 blocks/CU
    const int bid = blockIdx.x;
    const int bx = bid & 63, by = (bid >> 6) & 3, b = bid >> 8;
    const int w = threadIdx.x >> 6, lane = threadIdx.x & 63;
    const int lr = lane & 15, lg = lane >> 4;

    // --- staging plan: chunk cid = (w*5+g) mod 18; cid<8 -> A, else B ------
    const char* gp[5];   // per-chunk global base (incl. lane*16)
    int st[5];           // per-K-step stride of that chunk's source
    int lo[5];           // LDS byte offset within a step buffer
#pragma unroll
    for (int g = 0; g < 5; ++g) {
        int cid = w * 5 + g; if (cid >= 18) cid -= 18;
        if (cid < 8) {   // A: adjb tile (b*NMT+bx, kt), byte cid*1024
            gp[g] = adjb + (size_t)((b * NMT + bx) * NKT) * TILE_BYTES + cid * 1024 + lane * 16;
            st[g] = TILE_BYTES;
            lo[g] = cid * 1024;
        } else {         // B: Ytt tile (b*20 + by*5 + cc/2, kt), half cc&1
            int cc = cid - 8;
            gp[g] = ytt + (size_t)((b * 20 + by * 5 + (cc >> 1)) * 64) * YTILE + (cc & 1) * 1024 + lane * 16;
            st[g] = YTILE;
            lo[g] = 8192 + cc * 1024;
        }
    }

    // --- swizzled LDS read addresses ---------------------------------------
    uint32_t sb = (uint32_t)(uintptr_t)(__attribute__((address_space(3))) char*)smem;
    const int sw = (lr & 7) << 4;
    const uint32_t col0 = (uint32_t)((lg * 16) ^ sw);          // kh=0
    const uint32_t col1 = (uint32_t)(((4 + lg) * 16) ^ sw);    // kh=1
    const uint32_t rowA = sb + (w * 16 + lr) * 128;            // A rows w*16..+16
    uint32_t rowB[5];
#pragma unroll
    for (int nt = 0; nt < 5; ++nt) rowB[nt] = sb + 8192 + nt * YTILE + lr * 128;

    f32x4 acc[5] = {};
    uint32_t oc = 0, on = STEP_BYTES, ot = 2 * STEP_BYTES;

#define STAGE(OFF, KT_) { _Pragma("unroll") \
    for (int g = 0; g < 5; ++g) \
        gload_lds16(gp[g] + (size_t)(KT_) * st[g], smem + (OFF) + lo[g]); }

    // prologue: tiles 0,1 -> 10 outstanding per wave
    STAGE(oc, 0)
    STAGE(on, 1)
    for (int t = 0; t < NKT; ++t) {
        int ks = t + 2 > NKT - 1 ? NKT - 1 : t + 2;
        SB();
        STAGE(ot, ks)                         // +5 -> <=15 outstanding
        SB();
        asm volatile("s_waitcnt vmcnt(10)");  // tile t complete; t+1,t+2 in flight
        SB();
        __builtin_amdgcn_s_barrier();         // all waves' tile-t chunks landed
        bf16x8 a0, a1, b00, b01, b10, b11, b20, b21, b30, b31, b40, b41;
        asm volatile("ds_read_b128 %0, %1" : "=v"(a0)  : "v"(oc + rowA + col0));
        asm volatile("ds_read_b128 %0, %1" : "=v"(a1)  : "v"(oc + rowA + col1));
        asm volatile("ds_read_b128 %0, %1" : "=v"(b00) : "v"(oc + rowB[0] + col0));
        asm volatile("ds_read_b128 %0, %1" : "=v"(b01) : "v"(oc + rowB[0] + col1));
        asm volatile("ds_read_b128 %0, %1" : "=v"(b10) : "v"(oc + rowB[1] + col0));
        asm volatile("ds_read_b128 %0, %1" : "=v"(b11) : "v"(oc + rowB[1] + col1));
        asm volatile("ds_read_b128 %0, %1" : "=v"(b20) : "v"(oc + rowB[2] + col0));
        asm volatile("ds_read_b128 %0, %1" : "=v"(b21) : "v"(oc + rowB[2] + col1));
        asm volatile("ds_read_b128 %0, %1" : "=v"(b30) : "v"(oc + rowB[3] + col0));
        asm volatile("ds_read_b128 %0, %1" : "=v"(b31) : "v"(oc + rowB[3] + col1));
        asm volatile("ds_read_b128 %0, %1" : "=v"(b40) : "v"(oc + rowB[4] + col0));
        asm volatile("ds_read_b128 %0, %1" : "=v"(b41) : "v"(oc + rowB[4] + col1));
        asm volatile("s_waitcnt lgkmcnt(0)");
        SB();                                  // rule 18: fence MFMA below the wait
        __builtin_amdgcn_s_barrier();          // all waves done reading -> buf reusable
        acc[0] = __builtin_amdgcn_mfma_f32_16x16x32_bf16(a0, b00, acc[0], 0, 0, 0);
        acc[0] = __builtin_amdgcn_mfma_f32_16x16x32_bf16(a1, b01, acc[0], 0, 0, 0);
        acc[1] = __builtin_amdgcn_mfma_f32_16x16x32_bf16(a0, b10, acc[1], 0, 0, 0);
        acc[1] = __builtin_amdgcn_mfma_f32_16x16x32_bf16(a1, b11, acc[1], 0, 0, 0);
        acc[2] = __builtin_amdgcn_mfma_f32_16x16x32_bf16(a0, b20, acc[2], 0, 0, 0);
        acc[2] = __builtin_amdgcn_mfma_f32_16x16x32_bf16(a1, b21, acc[2], 0, 0, 0);
        acc[3] = __builtin_amdgcn_mfma_f32_16x16x32_bf16(a0, b30, acc[3], 0, 0, 0);
        acc[3] = __builtin_amdgcn_mfma_f32_16x16x32_bf16(a1, b31, acc[3], 0, 0, 0);
        acc[4] = __builtin_amdgcn_mfma_f32_16x16x32_bf16(a0, b40, acc[4], 0, 0, 0);
        acc[4] = __builtin_amdgcn_mfma_f32_16x16x32_bf16(a1, b41, acc[4], 0, 0, 0);
        SB();
        uint32_t tmp = oc; oc = on; on = ot; ot = tmp;   // rotate ring
    }

    // epilogue: scale by d_i, add bias, store (f < 300 only)
    const int rowb = bx * 64 + w * 16;
    float di[4];
#pragma unroll
    for (int r = 0; r < 4; ++r)
        di[r] = d[b * N_ + rowb + lg * 4 + r];
#pragma unroll
    for (int nt = 0; nt < 5; ++nt) {
        int f = by * 80 + nt * 16 + lr;
        if (f < FOUT) {
            float bv = bias[f];
#pragma unroll
            for (int r = 0; r < 4; ++r) {
                int i = rowb + lg * 4 + r;
                out[((size_t)b * N_ + i) * FOUT + f] = di[r] * acc[nt][r] + bv;
            }
        }
    }
#undef STAGE
}

// ---------------- Fallback GEMM (fp32 adj direct; only if ws too small) ----
#define FB_LOAD(AV, BV, K0)                                                           \
    {                                                                                 \
        _Pragma("unroll")                                                             \
        for (int mi = 0; mi < 2; ++mi) {                                              \
            const float4* p = (const float4*)(adjf + (size_t)(rowbase + mi * 16 + lr) * N_ + (K0) + lg * 8); \
            float4 v0 = p[0], v1 = p[1];                                              \
            AV[mi][0] = (__bf16)v0.x; AV[mi][1] = (__bf16)v0.y;                       \
            AV[mi][2] = (__bf16)v0.z; AV[mi][3] = (__bf16)v0.w;                       \
            AV[mi][4] = (__bf16)v1.x; AV[mi][5] = (__bf16)v1.y;                       \
            AV[mi][6] = (__bf16)v1.z; AV[mi][7] = (__bf16)v1.w;                       \
        }                                                                             \
        _Pragma("unroll")                                                             \
        for (int nt = 0; nt < 10; ++nt) {                                             \
            int f = wn * 160 + nt * 16 + lr;                                          \
            BV[nt] = *(const bf16x8*)(Yb + (size_t)f * N_ + (K0) + lg * 8);           \
        }                                                                             \
    }
#define FB_MFMA(AV, BV)                                                               \
    {                                                                                 \
        _Pragma("unroll")                                                             \
        for (int mi = 0; mi < 2; ++mi)                                                \
            _Pragma("unroll")                                                         \
            for (int nt = 0; nt < 10; ++nt)                                           \
                acc[mi][nt] = __builtin_amdgcn_mfma_f32_16x16x32_bf16(AV[mi], BV[nt], acc[mi][nt], 0, 0, 0); \
    }

__global__ __launch_bounds__(256) void k_gemm_fb(const float* __restrict__ adj,
                                                 const __bf16* __restrict__ Yt,
                                                 const float* __restrict__ d,
                                                 const float* __restrict__ bias,
                                                 float* __restrict__ out) {
    int b    = blockIdx.y;
    int wave = threadIdx.x >> 6, lane = threadIdx.x & 63;
    int wm = wave & 1, wn = wave >> 1;
    int lr = lane & 15, lg = lane >> 4;
    int rowbase = blockIdx.x * 64 + wm * 32;
    const float*  adjf = adj + (size_t)b * N_ * N_;
    const __bf16* Yb   = Yt + (size_t)b * FP * N_;

    f32x4 acc[2][10] = {};
    bf16x8 aA[2], bA[10], aB[2], bB[10];

    FB_LOAD(aA, bA, 0)
    for (int k0 = 0; k0 < N_ - 64; k0 += 64) {
        FB_LOAD(aB, bB, k0 + 32)
        FB_MFMA(aA, bA)
        FB_LOAD(aA, bA, k0 + 64)
        FB_MFMA(aB, bB)
    }
    FB_LOAD(aB, bB, N_ - 32)
    FB_MFMA(aA, bA)
    FB_MFMA(aB, bB)

#pragma unroll
    for (int mi = 0; mi < 2; ++mi) {
        float di[4];
#pragma unroll
        for (int r = 0; r < 4; ++r)
            di[r] = d[b * N_ + rowbase + mi * 16 + lg * 4 + r];
#pragma unroll
        for (int nt = 0; nt < 10; ++nt) {
            int f = wn * 160 + nt * 16 + lr;
            if (f < FOUT) {
                float bv = bias[f];
#pragma unroll
                for (int r = 0; r < 4; ++r) {
                    int i = rowbase + mi * 16 + lg * 4 + r;
                    out[((size_t)b * N_ + i) * FOUT + f] = di[r] * acc[mi][nt][r] + bv;
                }
            }
        }
    }
}

extern "C" void kernel_launch(void* const* d_in, const int* in_sizes, int n_in,
                              void* d_out, int out_size, void* d_ws, size_t ws_size,
                              hipStream_t stream) {
    const float* text = (const float*)d_in[0];
    const float* adj  = (const float*)d_in[1];
    const float* W    = (const float*)d_in[2];
    const float* bias = (const float*)d_in[3];
    float* out = (float*)d_out;

    char* ws = (char*)d_ws;
    __bf16* Wt   = (__bf16*)(ws + WT_OFF);
    float*  dv   = (float*)(ws + D_OFF);
    __bf16* Tsc  = (__bf16*)(ws + TSC_OFF);
    char*   Ybuf = ws + YT_OFF;
    char*   adjb = ws + ADJB_OFF;

    bool big = ws_size >= (size_t)ADJB_OFF + ADJB_BYTES;

    k_wt<<<dim3((FP * FP + 255) / 256), dim3(256), 0, stream>>>(W, Wt);
    if (big)
        k_rowsum_cvt<<<dim3(B_ * N_ / 4), dim3(256), 0, stream>>>(adj, dv, adjb);
    else
        k_rowsum<<<dim3(B_ * N_ / 4), dim3(256), 0, stream>>>(adj, dv);
    k_tsc<<<dim3(B_ * N_ * FP / 256), dim3(256), 0, stream>>>(text, dv, Tsc);
    if (big) {
        k_y_t<<<dim3(N_ / 64, B_), dim3(256), 0, stream>>>(Wt, Tsc, Ybuf);
        k_gemm_pipe<<<dim3(1024), dim3(256), 0, stream>>>(adjb, Ybuf, dv, bias, out);
    } else {
        k_y<<<dim3(N_ / 64, B_), dim3(256), 0, stream>>>(Wt, Tsc, (__bf16*)Ybuf);
        k_gemm_fb<<<dim3(N_ / 64, B_), dim3(256), 0, stream>>>(adj, (__bf16*)Ybuf, dv, bias, out);
    }
}